// Round 10
// baseline (190.957 us; speedup 1.0000x reference)
//
#include <hip/hip_runtime.h>
#include <hip/hip_bf16.h>

#define VOCAB 32000
#define EMBED 1024
#define SEQ 256
#define BATCH 8
#define ROWS (SEQ * BATCH) /* 2048 */

#define BM 256
#define BN 256
#define BK 64
#define NT (EMBED / BK) /* 16 K-tiles */

typedef short short8 __attribute__((ext_vector_type(8)));
typedef float f32x4 __attribute__((ext_vector_type(4)));

__device__ __forceinline__ unsigned short f2bf(float f) {
    __hip_bfloat16 h = __float2bfloat16(f);
    return *reinterpret_cast<unsigned short*>(&h);
}

#define GLOAD_LDS16(gsrc, ldst)                                                        \
    __builtin_amdgcn_global_load_lds((const __attribute__((address_space(1))) void*)(gsrc), \
                                     (__attribute__((address_space(3))) void*)(ldst), 16, 0, 0)

// ---------------- fused pre-pass: transpose (blocks 0..7999) + embed (blocks 8000..10047) ----------------
__global__ __launch_bounds__(256) void prep_k(const int* __restrict__ toks,
                                              const float* __restrict__ W1,
                                              const float* __restrict__ b1,
                                              const float* __restrict__ W2,
                                              unsigned short* __restrict__ h,
                                              unsigned short* __restrict__ W2t) {
    __shared__ float tile[64][65];
    int bid = blockIdx.x;
    int t = threadIdx.x;
    if (bid < 8000) {
        int n0 = (bid % 500) * 64;
        int k0 = (bid / 500) * 64;
        int tx = t & 15, ty = t >> 4;
#pragma unroll
        for (int p = 0; p < 4; ++p) {
            int k = ty + p * 16;
            float4 v = *(const float4*)(W2 + (size_t)(k0 + k) * VOCAB + n0 + tx * 4);
            tile[k][tx * 4 + 0] = v.x; tile[k][tx * 4 + 1] = v.y;
            tile[k][tx * 4 + 2] = v.z; tile[k][tx * 4 + 3] = v.w;
        }
        __syncthreads();
        int kx = t & 15, ny = t >> 4;
#pragma unroll
        for (int p = 0; p < 4; ++p) {
            int n = ny + p * 16;
            int k = kx * 4;
            union { unsigned short u[4]; uint2 v; } o;
            o.u[0] = f2bf(tile[k + 0][n]); o.u[1] = f2bf(tile[k + 1][n]);
            o.u[2] = f2bf(tile[k + 2][n]); o.u[3] = f2bf(tile[k + 3][n]);
            *(uint2*)(W2t + (size_t)(n0 + n) * EMBED + k0 + k) = o.v;
        }
    } else {
        int r = bid - 8000;
        int s = r >> 3, b = r & 7;
        int t0 = (s >= 3) ? toks[(s - 3) * BATCH + b] : 0;
        int t1 = (s >= 2) ? toks[(s - 2) * BATCH + b] : 0;
        int t2 = (s >= 1) ? toks[(s - 1) * BATCH + b] : 0;
        int e = t * 4;
        float4 vb = *(const float4*)(b1 + e);
        float4 v0 = *(const float4*)(W1 + ((size_t)0 * VOCAB + t0) * EMBED + e);
        float4 v1 = *(const float4*)(W1 + ((size_t)1 * VOCAB + t1) * EMBED + e);
        float4 v2 = *(const float4*)(W1 + ((size_t)2 * VOCAB + t2) * EMBED + e);
        float x0 = fmaxf(vb.x + v0.x + v1.x + v2.x, 0.0f);
        float x1 = fmaxf(vb.y + v0.y + v1.y + v2.y, 0.0f);
        float x2 = fmaxf(vb.z + v0.z + v1.z + v2.z, 0.0f);
        float x3 = fmaxf(vb.w + v0.w + v1.w + v2.w, 0.0f);
        union { unsigned short u[4]; uint2 v; } o;
        o.u[0] = f2bf(x0); o.u[1] = f2bf(x1); o.u[2] = f2bf(x2); o.u[3] = f2bf(x3);
        *(uint2*)(h + (size_t)r * EMBED + e) = o.v;
    }
}

// ---------------- persistent 256x256 8-phase bf16 MFMA GEMM: 4 m-tiles per block ----------------
// r9 skeleton (175 us: 16x16x32 MFMA, NT full-line epilogue via LDS-transpose T aliasing
// buf1.A, boundary prestages ONLY buf0.A, vmcnt(32), 128 KiB LDS, 250 blocks x 4 m-tiles).
// ONE mechanism changed: SINGLE trailing barrier per phase (was 2). Proof: every stage
// target's last readers are in a previous phase, whose ds_reads complete (own lgkmcnt(0))
// before that phase's trailing barrier -> leading barrier redundant for WAR; data-readiness
// is carried by the counted vmcnt(4)+barrier at ph4/ph8 (per-phase FIFO verified). WAITV
// moved after MFMA (overlaps load-wait with compute). Also: skip the DEAD it7 ph5/6 A-wrap
// stage - it raced the boundary's buf0.A prestage (two unordered in-flight writes, same LDS).
__global__ __launch_bounds__(512, 2) void gemm8_k(const unsigned short* __restrict__ A,
                                                  const unsigned short* __restrict__ B,
                                                  const float* __restrict__ b2,
                                                  float* __restrict__ out) {
    extern __shared__ char lds[];
    char* Al = lds;
    char* Bl = lds + 65536;

    // bijective XCD swizzle for 250 blocks (m204): q=31, r=2
    int wg = blockIdx.x;
    int xcd = wg & 7, idx = wg >> 3;
    int wgid = (xcd < 2 ? xcd * 32 : 2 * 32 + (xcd - 2) * 31) + idx;
    int mg = wgid & 1;            // m fast: stripe-sharing blocks adjacent
    int n0 = (wgid >> 1) * BN;    // 125 n-stripes
    int ms = mg * 1024;           // this block covers ms + {0,256,512,768}

    int tid = threadIdx.x;
    int w = tid >> 6, lane = tid & 63;
    int wm = w >> 2, wn = w & 3;
    int ksw = ((lane & 7) ^ ((lane >> 3) & 7)) * 8;

    f32x4 acc[8][4] = {};
    short8 af[2][2], bfr[4][2];

    auto stage = [&](const unsigned short* __restrict__ g, int grow0, char* ldsbase, int t) {
#pragma unroll
        for (int j = 0; j < 2; ++j) {
            int c = j * 8 + w;
            int row = c * 8 + (lane >> 3);
            const unsigned short* src = g + (size_t)(grow0 + row) * EMBED + t * BK + ksw;
            GLOAD_LDS16(src, ldsbase + c * 1024);
        }
    };
    auto stA = [&](int buf, int hh, int t, int mbase) { stage(A, mbase + hh * 128, Al + buf * 32768 + hh * 16384, t); };
    auto stB = [&](int buf, int hh, int t) { stage(B, n0 + hh * 128, Bl + buf * 32768 + hh * 16384, t); };

    auto ldA = [&](int buf, int qq) {
#pragma unroll
        for (int i = 0; i < 2; ++i)
#pragma unroll
            for (int kk = 0; kk < 2; ++kk) {
                int row = wm * 128 + (qq * 2 + i) * 16 + (lane & 15);
                int cb = ((lane >> 4) * 16 + kk * 64) ^ ((lane & 7) << 4);
                af[i][kk] = *(const short8*)(Al + buf * 32768 + row * 128 + cb);
            }
    };
    auto ldB = [&](int buf) {
#pragma unroll
        for (int n = 0; n < 4; ++n)
#pragma unroll
            for (int kk = 0; kk < 2; ++kk) {
                int row = wn * 64 + n * 16 + (lane & 15);
                int cb = ((lane >> 4) * 16 + kk * 64) ^ ((lane & 7) << 4);
                bfr[n][kk] = *(const short8*)(Bl + buf * 32768 + row * 128 + cb);
            }
    };

#define MFMA_Q(q)                                                                             \
    __builtin_amdgcn_s_setprio(1);                                                            \
    _Pragma("unroll") for (int i = 0; i < 2; ++i)                                             \
        _Pragma("unroll") for (int n = 0; n < 4; ++n)                                         \
            _Pragma("unroll") for (int kk = 0; kk < 2; ++kk)                                  \
                acc[(q)*2 + i][n] = __builtin_amdgcn_mfma_f32_16x16x32_bf16(                  \
                    af[i][kk], bfr[n][kk], acc[(q)*2 + i][n], 0, 0, 0);                       \
    __builtin_amdgcn_s_setprio(0);

// single TRAILING barrier per phase; WAITV (counted, never 0) after MFMA
#define PH(ldbuf, q, DO_LDB, STAGE_STMT, WAITV)                                               \
    ldA(ldbuf, q);                                                                            \
    if (DO_LDB) ldB(ldbuf);                                                                   \
    STAGE_STMT;                                                                               \
    asm volatile("s_waitcnt lgkmcnt(0)");                                                     \
    MFMA_Q(q);                                                                                \
    if (WAITV) asm volatile("s_waitcnt vmcnt(4)");                                            \
    __builtin_amdgcn_s_barrier();

    auto kloop = [&](int mcur) {
        for (int it = 0; it < NT / 2; ++it) {
            int t1 = (it * 2 + 1) & (NT - 1);
            int t2 = (it * 2 + 2) & (NT - 1);
            int t3 = (it * 2 + 3) & (NT - 1);
            bool w8 = (it == NT / 2 - 1);  // last it: A-wrap stage dead (boundary re-prestages)
            PH(0, 0, true,  stA(1, 0, t1, mcur), false)
            PH(0, 1, false, stA(1, 1, t1, mcur), false)
            PH(0, 2, false, stB(0, 0, t2),       false)
            PH(0, 3, false, stB(0, 1, t2),       true)
            PH(1, 0, true,  { if (!w8) stA(0, 0, t2, mcur); }, false)
            PH(1, 1, false, { if (!w8) stA(0, 1, t2, mcur); }, false)
            PH(1, 2, false, stB(1, 0, t3),       false)
            PH(1, 3, false, stB(1, 1, t3),       true)
        }
    };

    // ---- full-line NT epilogue via LDS transpose (dead buf1.A region, 32 KB) ----
    int colq = lane & 15;
    int rowq4 = (lane >> 4) * 4;
    auto epi = [&](int mbase) {
        char* T = Al + 32768;
        float bias[4];
#pragma unroll
        for (int nf = 0; nf < 4; ++nf) bias[nf] = b2[n0 + wn * 64 + nf * 16 + colq];
#pragma unroll
        for (int p = 0; p < 8; ++p) {
            __builtin_amdgcn_s_barrier();   // prior pass readback done before overwrite
            if (wm == (p >> 2)) {
#pragma unroll
                for (int mi = 0; mi < 2; ++mi) {
                    int mf = (p & 3) * 2 + mi;
                    int rl = mi * 16 + rowq4;
#pragma unroll
                    for (int nf = 0; nf < 4; ++nf) {
                        int c = wn * 64 + nf * 16 + colq;
#pragma unroll
                        for (int q = 0; q < 4; ++q)
                            *(float*)(T + (rl + q) * 1024 + c * 4) = acc[mf][nf][q] + bias[nf];
                    }
                }
            }
            __builtin_amdgcn_s_barrier();
#pragma unroll
            for (int rr = 0; rr < 4; ++rr) {
                int rl = w * 4 + rr;
                f32x4 v = *(const f32x4*)(T + rl * 1024 + lane * 16);
                int grow = mbase + p * 32 + rl;
                __builtin_nontemporal_store(v, (f32x4*)(out + (size_t)grow * VOCAB + n0 + lane * 4));
            }
        }
    };

    // ---- prologue (m-tile 0) ----
    stA(0, 0, 0, ms); stA(0, 1, 0, ms); stB(0, 0, 0); stB(0, 1, 0);
    stB(1, 0, 1); stB(1, 1, 1);
    asm volatile("s_waitcnt vmcnt(4)");
    __builtin_amdgcn_s_barrier();

    kloop(ms);

    // ---- 3 boundaries: wrap prefetch left buf0.B=B(t0), buf1.B=B(t1); buf0.A is NOT
    // wrap-staged (w8 skip) -> single writer. Prestage buf0.A=A(next,t0) before the
    // epilogue (T aliases buf1.A only). FIFO at vmcnt(32): 4 wrapB(ph7/8) + 4 prestageA
    // + 4 bias + 32 stores = 44 outstanding -> retires the 12 loads, stores untouched.
#pragma unroll 1
    for (int mt = 1; mt < 4; ++mt) {
        int mn = ms + mt * 256;
        stA(0, 0, 0, mn); stA(0, 1, 0, mn);
        epi(mn - 256);
        asm volatile("s_waitcnt vmcnt(32)" ::: "memory");
        __builtin_amdgcn_s_barrier();
#pragma unroll
        for (int mf = 0; mf < 8; ++mf)
#pragma unroll
            for (int nf = 0; nf < 4; ++nf)
                acc[mf][nf] = f32x4{0.f, 0.f, 0.f, 0.f};
        kloop(mn);
    }
    epi(ms + 768);
#undef PH
#undef MFMA_Q
}

// ---------------- fallback 128^2 2-phase GEMM (if 128 KiB dyn LDS unavailable) ----------------
__global__ __launch_bounds__(256) void gemm_k(const unsigned short* __restrict__ h,
                                              const unsigned short* __restrict__ W2t,
                                              const float* __restrict__ b2,
                                              float* __restrict__ out) {
    __shared__ unsigned short Alds[128 * 64];
    __shared__ unsigned short Blds[128 * 64];
    int m0 = blockIdx.x * 128;
    int n0 = blockIdx.y * 128;
    int tid = threadIdx.x;
    int wave = tid >> 6, lane = tid & 63;
    int wr = (wave >> 1) * 64;
    int wc = (wave & 1) * 64;
    int lrow = lane & 15;
    int khalf = (lane >> 4) * 8;
    f32x4 acc[4][4] = {};
    for (int kt = 0; kt < EMBED; kt += 64) {
#pragma unroll
        for (int i = 0; i < 4; ++i) {
            int base = (wave * 4 + i) * 1024;
            int lin = base + lane * 16;
            int row = lin >> 7;
            int colu = (lin & 127) >> 1;
            GLOAD_LDS16(h + (size_t)(m0 + row) * EMBED + kt + colu, (char*)Alds + base);
            GLOAD_LDS16(W2t + (size_t)(n0 + row) * EMBED + kt + colu, (char*)Blds + base);
        }
        __syncthreads();
#pragma unroll
        for (int kc = 0; kc < 2; ++kc) {
            short8 af[4], bf[4];
#pragma unroll
            for (int m = 0; m < 4; ++m)
                af[m] = *(const short8*)(Alds + (wr + m * 16 + lrow) * 64 + kc * 32 + khalf);
#pragma unroll
            for (int n = 0; n < 4; ++n)
                bf[n] = *(const short8*)(Blds + (wc + n * 16 + lrow) * 64 + kc * 32 + khalf);
#pragma unroll
            for (int m = 0; m < 4; ++m)
#pragma unroll
                for (int n = 0; n < 4; ++n)
                    acc[m][n] = __builtin_amdgcn_mfma_f32_16x16x32_bf16(af[m], bf[n], acc[m][n], 0, 0, 0);
        }
        __syncthreads();
    }
    int colq = lane & 15;
    int rowq = (lane >> 4) * 4;
#pragma unroll
    for (int m = 0; m < 4; ++m)
#pragma unroll
        for (int n = 0; n < 4; ++n) {
            int col = n0 + wc + n * 16 + colq;
            float bias = b2[col];
#pragma unroll
            for (int q = 0; q < 4; ++q)
                out[(size_t)(m0 + wr + m * 16 + rowq + q) * VOCAB + col] = acc[m][n][q] + bias;
        }
}

// ---------------- fallback (ws too small): correct fp32 path ----------------
__global__ __launch_bounds__(256) void naive_k(const int* __restrict__ toks,
                                               const float* __restrict__ W1,
                                               const float* __restrict__ b1,
                                               const float* __restrict__ W2,
                                               const float* __restrict__ b2,
                                               float* __restrict__ out) {
    __shared__ float hs[8][1024];
    int r0 = blockIdx.x * 8;
    int e = threadIdx.x * 4;
    for (int rr = 0; rr < 8; ++rr) {
        int r = r0 + rr, s = r >> 3, b = r & 7;
        int t0 = (s >= 3) ? toks[(s - 3) * BATCH + b] : 0;
        int t1 = (s >= 2) ? toks[(s - 2) * BATCH + b] : 0;
        int t2 = (s >= 1) ? toks[(s - 1) * BATCH + b] : 0;
        float4 vb = *(const float4*)(b1 + e);
        float4 v0 = *(const float4*)(W1 + ((size_t)t0) * EMBED + e);
        float4 v1 = *(const float4*)(W1 + ((size_t)VOCAB + t1) * EMBED + e);
        float4 v2 = *(const float4*)(W1 + ((size_t)2 * VOCAB + t2) * EMBED + e);
        hs[rr][e + 0] = fmaxf(vb.x + v0.x + v1.x + v2.x, 0.0f);
        hs[rr][e + 1] = fmaxf(vb.y + v0.y + v1.y + v2.y, 0.0f);
        hs[rr][e + 2] = fmaxf(vb.z + v0.z + v1.z + v2.z, 0.0f);
        hs[rr][e + 3] = fmaxf(vb.w + v0.w + v1.w + v2.w, 0.0f);
    }
    __syncthreads();
    for (int v = threadIdx.x; v < VOCAB; v += 256) {
        float acc[8];
#pragma unroll
        for (int i = 0; i < 8; ++i) acc[i] = b2[v];
        for (int ee = 0; ee < EMBED; ++ee) {
            float wv = W2[(size_t)ee * VOCAB + v];
#pragma unroll
            for (int i = 0; i < 8; ++i) acc[i] += hs[i][ee] * wv;
        }
#pragma unroll
        for (int i = 0; i < 8; ++i) out[(size_t)(r0 + i) * VOCAB + v] = acc[i];
    }
}

extern "C" void kernel_launch(void* const* d_in, const int* in_sizes, int n_in,
                              void* d_out, int out_size, void* d_ws, size_t ws_size,
                              hipStream_t stream) {
    const int* toks = (const int*)d_in[0];
    const float* W1 = (const float*)d_in[1];
    const float* b1 = (const float*)d_in[2];
    const float* W2 = (const float*)d_in[3];
    const float* b2 = (const float*)d_in[4];
    float* out = (float*)d_out;

    const size_t h_bytes = (size_t)ROWS * EMBED * 2;
    const size_t w2t_bytes = (size_t)VOCAB * EMBED * 2;
    if (ws_size >= h_bytes + w2t_bytes) {
        unsigned short* h = (unsigned short*)d_ws;
        unsigned short* W2t = (unsigned short*)((char*)d_ws + h_bytes);
        prep_k<<<8000 + ROWS, 256, 0, stream>>>(toks, W1, b1, W2, h, W2t);
        hipError_t e = hipFuncSetAttribute(reinterpret_cast<const void*>(gemm8_k),
                                           hipFuncAttributeMaxDynamicSharedMemorySize, 131072);
        if (e == hipSuccess) {
            gemm8_k<<<(ROWS / 1024) * (VOCAB / BN), 512, 131072, stream>>>(h, W2t, b2, out);
        } else {
            gemm_k<<<dim3(ROWS / 128, VOCAB / 128), 256, 0, stream>>>(h, W2t, b2, out);
        }
    } else {
        naive_k<<<ROWS / 8, 256, 0, stream>>>(toks, W1, b1, W2, b2, out);
    }
}

// Round 12
// 181.571 us; speedup vs baseline: 1.0517x; 1.0517x over previous
//
#include <hip/hip_runtime.h>
#include <hip/hip_bf16.h>

#define VOCAB 32000
#define EMBED 1024
#define SEQ 256
#define BATCH 8
#define ROWS (SEQ * BATCH) /* 2048 */

#define BM 256
#define BN 256
#define BK 64
#define NT (EMBED / BK) /* 16 K-tiles */

typedef short short8 __attribute__((ext_vector_type(8)));
typedef float f32x4 __attribute__((ext_vector_type(4)));

__device__ __forceinline__ unsigned short f2bf(float f) {
    __hip_bfloat16 h = __float2bfloat16(f);
    return *reinterpret_cast<unsigned short*>(&h);
}

#define GLOAD_LDS16(gsrc, ldst)                                                        \
    __builtin_amdgcn_global_load_lds((const __attribute__((address_space(1))) void*)(gsrc), \
                                     (__attribute__((address_space(3))) void*)(ldst), 16, 0, 0)

// ---------------- fused pre-pass: transpose (blocks 0..7999) + embed (blocks 8000..10047) ----
// NT (no-allocate) loads on the DEAD streams (W2 fp32, W1 rows): read once, never reused --
// keeping them out of L2/L3 leaves the caches to retain W2t/h, the data gemm8 re-reads.
// (r1 FETCH=273MB showed B re-fetched ~4x from HBM; this targets that.)
// NOTE: __builtin_nontemporal_load needs a TRUE vector type (ext_vector_type), not
// HIP_vector_type float4 -- r11 compile fail.
__global__ __launch_bounds__(256) void prep_k(const int* __restrict__ toks,
                                              const float* __restrict__ W1,
                                              const float* __restrict__ b1,
                                              const float* __restrict__ W2,
                                              unsigned short* __restrict__ h,
                                              unsigned short* __restrict__ W2t) {
    __shared__ float tile[64][65];
    int bid = blockIdx.x;
    int t = threadIdx.x;
    if (bid < 8000) {
        int n0 = (bid % 500) * 64;
        int k0 = (bid / 500) * 64;
        int tx = t & 15, ty = t >> 4;
#pragma unroll
        for (int p = 0; p < 4; ++p) {
            int k = ty + p * 16;
            f32x4 v = __builtin_nontemporal_load(
                (const f32x4*)(W2 + (size_t)(k0 + k) * VOCAB + n0 + tx * 4));
            tile[k][tx * 4 + 0] = v[0]; tile[k][tx * 4 + 1] = v[1];
            tile[k][tx * 4 + 2] = v[2]; tile[k][tx * 4 + 3] = v[3];
        }
        __syncthreads();
        int kx = t & 15, ny = t >> 4;
#pragma unroll
        for (int p = 0; p < 4; ++p) {
            int n = ny + p * 16;
            int k = kx * 4;
            union { unsigned short u[4]; uint2 v; } o;
            o.u[0] = f2bf(tile[k + 0][n]); o.u[1] = f2bf(tile[k + 1][n]);
            o.u[2] = f2bf(tile[k + 2][n]); o.u[3] = f2bf(tile[k + 3][n]);
            *(uint2*)(W2t + (size_t)(n0 + n) * EMBED + k0 + k) = o.v;
        }
    } else {
        int r = bid - 8000;
        int s = r >> 3, b = r & 7;
        int t0 = (s >= 3) ? toks[(s - 3) * BATCH + b] : 0;
        int t1 = (s >= 2) ? toks[(s - 2) * BATCH + b] : 0;
        int t2 = (s >= 1) ? toks[(s - 1) * BATCH + b] : 0;
        int e = t * 4;
        f32x4 vb = *(const f32x4*)(b1 + e);
        f32x4 v0 = __builtin_nontemporal_load((const f32x4*)(W1 + ((size_t)0 * VOCAB + t0) * EMBED + e));
        f32x4 v1 = __builtin_nontemporal_load((const f32x4*)(W1 + ((size_t)1 * VOCAB + t1) * EMBED + e));
        f32x4 v2 = __builtin_nontemporal_load((const f32x4*)(W1 + ((size_t)2 * VOCAB + t2) * EMBED + e));
        float x0 = fmaxf(vb[0] + v0[0] + v1[0] + v2[0], 0.0f);
        float x1 = fmaxf(vb[1] + v0[1] + v1[1] + v2[1], 0.0f);
        float x2 = fmaxf(vb[2] + v0[2] + v1[2] + v2[2], 0.0f);
        float x3 = fmaxf(vb[3] + v0[3] + v1[3] + v2[3], 0.0f);
        union { unsigned short u[4]; uint2 v; } o;
        o.u[0] = f2bf(x0); o.u[1] = f2bf(x1); o.u[2] = f2bf(x2); o.u[3] = f2bf(x3);
        *(uint2*)(h + (size_t)r * EMBED + e) = o.v;
    }
}

// ---------------- persistent 256x256 8-phase bf16 MFMA GEMM: 4 m-tiles per block ----------------
// r9 checkpoint EXACTLY (175.2 us): 16x16x32 MFMA, dual-barrier phases (leading barrier
// hides ds_read latency behind cross-wave sync -- r10 proved removing it costs ~9%),
// NT full-line epilogue via LDS-transpose T aliasing buf1.A, boundary prestages ONLY
// buf0.A, vmcnt(32), 128 KiB LDS, 250 blocks x 4 m-tiles.
__global__ __launch_bounds__(512, 2) void gemm8_k(const unsigned short* __restrict__ A,
                                                  const unsigned short* __restrict__ B,
                                                  const float* __restrict__ b2,
                                                  float* __restrict__ out) {
    extern __shared__ char lds[];
    char* Al = lds;
    char* Bl = lds + 65536;

    // bijective XCD swizzle for 250 blocks (m204): q=31, r=2
    int wg = blockIdx.x;
    int xcd = wg & 7, idx = wg >> 3;
    int wgid = (xcd < 2 ? xcd * 32 : 2 * 32 + (xcd - 2) * 31) + idx;
    int mg = wgid & 1;            // m fast: stripe-sharing blocks adjacent (same XCD chunk)
    int n0 = (wgid >> 1) * BN;    // 125 n-stripes
    int ms = mg * 1024;           // this block covers ms + {0,256,512,768}

    int tid = threadIdx.x;
    int w = tid >> 6, lane = tid & 63;
    int wm = w >> 2, wn = w & 3;
    int ksw = ((lane & 7) ^ ((lane >> 3) & 7)) * 8;

    f32x4 acc[8][4] = {};
    short8 af[2][2], bfr[4][2];

    auto stage = [&](const unsigned short* __restrict__ g, int grow0, char* ldsbase, int t) {
#pragma unroll
        for (int j = 0; j < 2; ++j) {
            int c = j * 8 + w;
            int row = c * 8 + (lane >> 3);
            const unsigned short* src = g + (size_t)(grow0 + row) * EMBED + t * BK + ksw;
            GLOAD_LDS16(src, ldsbase + c * 1024);
        }
    };
    auto stA = [&](int buf, int hh, int t, int mbase) { stage(A, mbase + hh * 128, Al + buf * 32768 + hh * 16384, t); };
    auto stB = [&](int buf, int hh, int t) { stage(B, n0 + hh * 128, Bl + buf * 32768 + hh * 16384, t); };

    auto ldA = [&](int buf, int qq) {
#pragma unroll
        for (int i = 0; i < 2; ++i)
#pragma unroll
            for (int kk = 0; kk < 2; ++kk) {
                int row = wm * 128 + (qq * 2 + i) * 16 + (lane & 15);
                int cb = ((lane >> 4) * 16 + kk * 64) ^ ((lane & 7) << 4);
                af[i][kk] = *(const short8*)(Al + buf * 32768 + row * 128 + cb);
            }
    };
    auto ldB = [&](int buf) {
#pragma unroll
        for (int n = 0; n < 4; ++n)
#pragma unroll
            for (int kk = 0; kk < 2; ++kk) {
                int row = wn * 64 + n * 16 + (lane & 15);
                int cb = ((lane >> 4) * 16 + kk * 64) ^ ((lane & 7) << 4);
                bfr[n][kk] = *(const short8*)(Bl + buf * 32768 + row * 128 + cb);
            }
    };

#define MFMA_Q(q)                                                                             \
    __builtin_amdgcn_s_setprio(1);                                                            \
    _Pragma("unroll") for (int i = 0; i < 2; ++i)                                             \
        _Pragma("unroll") for (int n = 0; n < 4; ++n)                                         \
            _Pragma("unroll") for (int kk = 0; kk < 2; ++kk)                                  \
                acc[(q)*2 + i][n] = __builtin_amdgcn_mfma_f32_16x16x32_bf16(                  \
                    af[i][kk], bfr[n][kk], acc[(q)*2 + i][n], 0, 0, 0);                       \
    __builtin_amdgcn_s_setprio(0);

#define PH(ldbuf, q, DO_LDB, STAGE_STMT, WAITV)                                               \
    ldA(ldbuf, q);                                                                            \
    if (DO_LDB) ldB(ldbuf);                                                                   \
    STAGE_STMT;                                                                               \
    if (DO_LDB) asm volatile("s_waitcnt lgkmcnt(8)");                                         \
    if (WAITV) asm volatile("s_waitcnt vmcnt(4)");                                            \
    __builtin_amdgcn_s_barrier();                                                             \
    asm volatile("s_waitcnt lgkmcnt(0)");                                                     \
    MFMA_Q(q);                                                                                \
    __builtin_amdgcn_s_barrier();

    auto kloop = [&](int mcur) {
        for (int it = 0; it < NT / 2; ++it) {
            int t1 = (it * 2 + 1) & (NT - 1);
            int t2 = (it * 2 + 2) & (NT - 1);
            int t3 = (it * 2 + 3) & (NT - 1);
            PH(0, 0, true,  stA(1, 0, t1, mcur), false)
            PH(0, 1, false, stA(1, 1, t1, mcur), false)
            PH(0, 2, false, stB(0, 0, t2),       false)
            PH(0, 3, false, stB(0, 1, t2),       true)
            PH(1, 0, true,  stA(0, 0, t2, mcur), false)
            PH(1, 1, false, stA(0, 1, t2, mcur), false)
            PH(1, 2, false, stB(1, 0, t3),       false)
            PH(1, 3, false, stB(1, 1, t3),       true)
        }
    };

    // ---- full-line NT epilogue via LDS transpose (dead buf1.A region, 32 KB) ----
    int colq = lane & 15;
    int rowq4 = (lane >> 4) * 4;
    auto epi = [&](int mbase) {
        char* T = Al + 32768;
        float bias[4];
#pragma unroll
        for (int nf = 0; nf < 4; ++nf) bias[nf] = b2[n0 + wn * 64 + nf * 16 + colq];
#pragma unroll
        for (int p = 0; p < 8; ++p) {
            __builtin_amdgcn_s_barrier();   // prior pass readback done before overwrite
            if (wm == (p >> 2)) {
#pragma unroll
                for (int mi = 0; mi < 2; ++mi) {
                    int mf = (p & 3) * 2 + mi;
                    int rl = mi * 16 + rowq4;
#pragma unroll
                    for (int nf = 0; nf < 4; ++nf) {
                        int c = wn * 64 + nf * 16 + colq;
#pragma unroll
                        for (int q = 0; q < 4; ++q)
                            *(float*)(T + (rl + q) * 1024 + c * 4) = acc[mf][nf][q] + bias[nf];
                    }
                }
            }
            __builtin_amdgcn_s_barrier();
#pragma unroll
            for (int rr = 0; rr < 4; ++rr) {
                int rl = w * 4 + rr;
                f32x4 v = *(const f32x4*)(T + rl * 1024 + lane * 16);
                int grow = mbase + p * 32 + rl;
                __builtin_nontemporal_store(v, (f32x4*)(out + (size_t)grow * VOCAB + n0 + lane * 4));
            }
        }
    };

    // ---- prologue (m-tile 0) ----
    stA(0, 0, 0, ms); stA(0, 1, 0, ms); stB(0, 0, 0); stB(0, 1, 0);
    stB(1, 0, 1); stB(1, 1, 1);
    asm volatile("s_waitcnt vmcnt(4)");
    __builtin_amdgcn_s_barrier();

    kloop(ms);

    // ---- 3 boundaries (r5 semantics): wrap prefetch left buf0.B=B(t0), buf1.B=B(t1).
    // Prestage ONLY buf0.A with A(next,t0) before the epilogue (T aliases buf1.A).
    // FIFO at vmcnt(32): 4 wrapB + 4 prestageA + 4 bias + 32 stores = 44 outstanding
    // -> retires the 12 loads, stores untouched.
#pragma unroll 1
    for (int mt = 1; mt < 4; ++mt) {
        int mn = ms + mt * 256;
        stA(0, 0, 0, mn); stA(0, 1, 0, mn);
        epi(mn - 256);
        asm volatile("s_waitcnt vmcnt(32)" ::: "memory");
        __builtin_amdgcn_s_barrier();
#pragma unroll
        for (int mf = 0; mf < 8; ++mf)
#pragma unroll
            for (int nf = 0; nf < 4; ++nf)
                acc[mf][nf] = f32x4{0.f, 0.f, 0.f, 0.f};
        kloop(mn);
    }
    epi(ms + 768);
#undef PH
#undef MFMA_Q
}

// ---------------- fallback 128^2 2-phase GEMM (if 128 KiB dyn LDS unavailable) ----------------
__global__ __launch_bounds__(256) void gemm_k(const unsigned short* __restrict__ h,
                                              const unsigned short* __restrict__ W2t,
                                              const float* __restrict__ b2,
                                              float* __restrict__ out) {
    __shared__ unsigned short Alds[128 * 64];
    __shared__ unsigned short Blds[128 * 64];
    int m0 = blockIdx.x * 128;
    int n0 = blockIdx.y * 128;
    int tid = threadIdx.x;
    int wave = tid >> 6, lane = tid & 63;
    int wr = (wave >> 1) * 64;
    int wc = (wave & 1) * 64;
    int lrow = lane & 15;
    int khalf = (lane >> 4) * 8;
    f32x4 acc[4][4] = {};
    for (int kt = 0; kt < EMBED; kt += 64) {
#pragma unroll
        for (int i = 0; i < 4; ++i) {
            int base = (wave * 4 + i) * 1024;
            int lin = base + lane * 16;
            int row = lin >> 7;
            int colu = (lin & 127) >> 1;
            GLOAD_LDS16(h + (size_t)(m0 + row) * EMBED + kt + colu, (char*)Alds + base);
            GLOAD_LDS16(W2t + (size_t)(n0 + row) * EMBED + kt + colu, (char*)Blds + base);
        }
        __syncthreads();
#pragma unroll
        for (int kc = 0; kc < 2; ++kc) {
            short8 af[4], bf[4];
#pragma unroll
            for (int m = 0; m < 4; ++m)
                af[m] = *(const short8*)(Alds + (wr + m * 16 + lrow) * 64 + kc * 32 + khalf);
#pragma unroll
            for (int n = 0; n < 4; ++n)
                bf[n] = *(const short8*)(Blds + (wc + n * 16 + lrow) * 64 + kc * 32 + khalf);
#pragma unroll
            for (int m = 0; m < 4; ++m)
#pragma unroll
                for (int n = 0; n < 4; ++n)
                    acc[m][n] = __builtin_amdgcn_mfma_f32_16x16x32_bf16(af[m], bf[n], acc[m][n], 0, 0, 0);
        }
        __syncthreads();
    }
    int colq = lane & 15;
    int rowq = (lane >> 4) * 4;
#pragma unroll
    for (int m = 0; m < 4; ++m)
#pragma unroll
        for (int n = 0; n < 4; ++n) {
            int col = n0 + wc + n * 16 + colq;
            float bias = b2[col];
#pragma unroll
            for (int q = 0; q < 4; ++q)
                out[(size_t)(m0 + wr + m * 16 + rowq + q) * VOCAB + col] = acc[m][n][q] + bias;
        }
}

// ---------------- fallback (ws too small): correct fp32 path ----------------
__global__ __launch_bounds__(256) void naive_k(const int* __restrict__ toks,
                                               const float* __restrict__ W1,
                                               const float* __restrict__ b1,
                                               const float* __restrict__ W2,
                                               const float* __restrict__ b2,
                                               float* __restrict__ out) {
    __shared__ float hs[8][1024];
    int r0 = blockIdx.x * 8;
    int e = threadIdx.x * 4;
    for (int rr = 0; rr < 8; ++rr) {
        int r = r0 + rr, s = r >> 3, b = r & 7;
        int t0 = (s >= 3) ? toks[(s - 3) * BATCH + b] : 0;
        int t1 = (s >= 2) ? toks[(s - 2) * BATCH + b] : 0;
        int t2 = (s >= 1) ? toks[(s - 1) * BATCH + b] : 0;
        float4 vb = *(const float4*)(b1 + e);
        float4 v0 = *(const float4*)(W1 + ((size_t)t0) * EMBED + e);
        float4 v1 = *(const float4*)(W1 + ((size_t)VOCAB + t1) * EMBED + e);
        float4 v2 = *(const float4*)(W1 + ((size_t)2 * VOCAB + t2) * EMBED + e);
        hs[rr][e + 0] = fmaxf(vb.x + v0.x + v1.x + v2.x, 0.0f);
        hs[rr][e + 1] = fmaxf(vb.y + v0.y + v1.y + v2.y, 0.0f);
        hs[rr][e + 2] = fmaxf(vb.z + v0.z + v1.z + v2.z, 0.0f);
        hs[rr][e + 3] = fmaxf(vb.w + v0.w + v1.w + v2.w, 0.0f);
    }
    __syncthreads();
    for (int v = threadIdx.x; v < VOCAB; v += 256) {
        float acc[8];
#pragma unroll
        for (int i = 0; i < 8; ++i) acc[i] = b2[v];
        for (int ee = 0; ee < EMBED; ++ee) {
            float wv = W2[(size_t)ee * VOCAB + v];
#pragma unroll
            for (int i = 0; i < 8; ++i) acc[i] += hs[i][ee] * wv;
        }
#pragma unroll
        for (int i = 0; i < 8; ++i) out[(size_t)(r0 + i) * VOCAB + v] = acc[i];
    }
}

extern "C" void kernel_launch(void* const* d_in, const int* in_sizes, int n_in,
                              void* d_out, int out_size, void* d_ws, size_t ws_size,
                              hipStream_t stream) {
    const int* toks = (const int*)d_in[0];
    const float* W1 = (const float*)d_in[1];
    const float* b1 = (const float*)d_in[2];
    const float* W2 = (const float*)d_in[3];
    const float* b2 = (const float*)d_in[4];
    float* out = (float*)d_out;

    const size_t h_bytes = (size_t)ROWS * EMBED * 2;
    const size_t w2t_bytes = (size_t)VOCAB * EMBED * 2;
    if (ws_size >= h_bytes + w2t_bytes) {
        unsigned short* h = (unsigned short*)d_ws;
        unsigned short* W2t = (unsigned short*)((char*)d_ws + h_bytes);
        prep_k<<<8000 + ROWS, 256, 0, stream>>>(toks, W1, b1, W2, h, W2t);
        hipError_t e = hipFuncSetAttribute(reinterpret_cast<const void*>(gemm8_k),
                                           hipFuncAttributeMaxDynamicSharedMemorySize, 131072);
        if (e == hipSuccess) {
            gemm8_k<<<(ROWS / 1024) * (VOCAB / BN), 512, 131072, stream>>>(h, W2t, b2, out);
        } else {
            gemm_k<<<dim3(ROWS / 128, VOCAB / 128), 256, 0, stream>>>(h, W2t, b2, out);
        }
    } else {
        naive_k<<<ROWS / 8, 256, 0, stream>>>(toks, W1, b1, W2, b2, out);
    }
}

// Round 13
// 176.345 us; speedup vs baseline: 1.0829x; 1.0296x over previous
//
#include <hip/hip_runtime.h>
#include <hip/hip_bf16.h>

#define VOCAB 32000
#define EMBED 1024
#define SEQ 256
#define BATCH 8
#define ROWS (SEQ * BATCH) /* 2048 */

#define BM 256
#define BN 256
#define BK 64
#define NT (EMBED / BK) /* 16 K-tiles */

typedef short short8 __attribute__((ext_vector_type(8)));
typedef float f32x4 __attribute__((ext_vector_type(4)));

__device__ __forceinline__ unsigned short f2bf(float f) {
    __hip_bfloat16 h = __float2bfloat16(f);
    return *reinterpret_cast<unsigned short*>(&h);
}

#define GLOAD_LDS16(gsrc, ldst)                                                        \
    __builtin_amdgcn_global_load_lds((const __attribute__((address_space(1))) void*)(gsrc), \
                                     (__attribute__((address_space(3))) void*)(ldst), 16, 0, 0)

// ---------------- fused pre-pass: transpose (blocks 0..7999) + embed (blocks 8000..10047) ----
// Plain (allocating) loads: r12 proved NT loads here cost ~6 us.
__global__ __launch_bounds__(256) void prep_k(const int* __restrict__ toks,
                                              const float* __restrict__ W1,
                                              const float* __restrict__ b1,
                                              const float* __restrict__ W2,
                                              unsigned short* __restrict__ h,
                                              unsigned short* __restrict__ W2t) {
    __shared__ float tile[64][65];
    int bid = blockIdx.x;
    int t = threadIdx.x;
    if (bid < 8000) {
        int n0 = (bid % 500) * 64;
        int k0 = (bid / 500) * 64;
        int tx = t & 15, ty = t >> 4;
#pragma unroll
        for (int p = 0; p < 4; ++p) {
            int k = ty + p * 16;
            float4 v = *(const float4*)(W2 + (size_t)(k0 + k) * VOCAB + n0 + tx * 4);
            tile[k][tx * 4 + 0] = v.x; tile[k][tx * 4 + 1] = v.y;
            tile[k][tx * 4 + 2] = v.z; tile[k][tx * 4 + 3] = v.w;
        }
        __syncthreads();
        int kx = t & 15, ny = t >> 4;
#pragma unroll
        for (int p = 0; p < 4; ++p) {
            int n = ny + p * 16;
            int k = kx * 4;
            union { unsigned short u[4]; uint2 v; } o;
            o.u[0] = f2bf(tile[k + 0][n]); o.u[1] = f2bf(tile[k + 1][n]);
            o.u[2] = f2bf(tile[k + 2][n]); o.u[3] = f2bf(tile[k + 3][n]);
            *(uint2*)(W2t + (size_t)(n0 + n) * EMBED + k0 + k) = o.v;
        }
    } else {
        int r = bid - 8000;
        int s = r >> 3, b = r & 7;
        int t0 = (s >= 3) ? toks[(s - 3) * BATCH + b] : 0;
        int t1 = (s >= 2) ? toks[(s - 2) * BATCH + b] : 0;
        int t2 = (s >= 1) ? toks[(s - 1) * BATCH + b] : 0;
        int e = t * 4;
        float4 vb = *(const float4*)(b1 + e);
        float4 v0 = *(const float4*)(W1 + ((size_t)0 * VOCAB + t0) * EMBED + e);
        float4 v1 = *(const float4*)(W1 + ((size_t)1 * VOCAB + t1) * EMBED + e);
        float4 v2 = *(const float4*)(W1 + ((size_t)2 * VOCAB + t2) * EMBED + e);
        float x0 = fmaxf(vb.x + v0.x + v1.x + v2.x, 0.0f);
        float x1 = fmaxf(vb.y + v0.y + v1.y + v2.y, 0.0f);
        float x2 = fmaxf(vb.z + v0.z + v1.z + v2.z, 0.0f);
        float x3 = fmaxf(vb.w + v0.w + v1.w + v2.w, 0.0f);
        union { unsigned short u[4]; uint2 v; } o;
        o.u[0] = f2bf(x0); o.u[1] = f2bf(x1); o.u[2] = f2bf(x2); o.u[3] = f2bf(x3);
        *(uint2*)(h + (size_t)r * EMBED + e) = o.v;
    }
}

// ---------------- persistent 256x256 8-phase bf16 MFMA GEMM: 4 m-tiles per block ----------------
// r9 checkpoint (175.2 us): 16x16x32 MFMA, dual-barrier phases (leading barrier hides
// ds_read latency behind cross-wave sync -- r10: removing it costs ~9%), NT full-line
// epilogue via LDS-transpose T aliasing buf1.A, boundary prestages ONLY buf0.A,
// vmcnt(32), 128 KiB LDS, 250 blocks x 4 m-tiles. Δr13: b2 bias hoisted out of epi
// (m-tile-invariant; removes 12 redundant loads from the boundary vmem FIFO).
__global__ __launch_bounds__(512, 2) void gemm8_k(const unsigned short* __restrict__ A,
                                                  const unsigned short* __restrict__ B,
                                                  const float* __restrict__ b2,
                                                  float* __restrict__ out) {
    extern __shared__ char lds[];
    char* Al = lds;
    char* Bl = lds + 65536;

    // bijective XCD swizzle for 250 blocks (m204): q=31, r=2
    int wg = blockIdx.x;
    int xcd = wg & 7, idx = wg >> 3;
    int wgid = (xcd < 2 ? xcd * 32 : 2 * 32 + (xcd - 2) * 31) + idx;
    int mg = wgid & 1;            // m fast: stripe-sharing blocks adjacent (same XCD chunk)
    int n0 = (wgid >> 1) * BN;    // 125 n-stripes
    int ms = mg * 1024;           // this block covers ms + {0,256,512,768}

    int tid = threadIdx.x;
    int w = tid >> 6, lane = tid & 63;
    int wm = w >> 2, wn = w & 3;
    int ksw = ((lane & 7) ^ ((lane >> 3) & 7)) * 8;

    f32x4 acc[8][4] = {};
    short8 af[2][2], bfr[4][2];

    // bias: m-tile-invariant, loaded ONCE (kept in 4 VGPRs for the whole kernel)
    int colq = lane & 15;
    float bias[4];
#pragma unroll
    for (int nf = 0; nf < 4; ++nf) bias[nf] = b2[n0 + wn * 64 + nf * 16 + colq];

    auto stage = [&](const unsigned short* __restrict__ g, int grow0, char* ldsbase, int t) {
#pragma unroll
        for (int j = 0; j < 2; ++j) {
            int c = j * 8 + w;
            int row = c * 8 + (lane >> 3);
            const unsigned short* src = g + (size_t)(grow0 + row) * EMBED + t * BK + ksw;
            GLOAD_LDS16(src, ldsbase + c * 1024);
        }
    };
    auto stA = [&](int buf, int hh, int t, int mbase) { stage(A, mbase + hh * 128, Al + buf * 32768 + hh * 16384, t); };
    auto stB = [&](int buf, int hh, int t) { stage(B, n0 + hh * 128, Bl + buf * 32768 + hh * 16384, t); };

    auto ldA = [&](int buf, int qq) {
#pragma unroll
        for (int i = 0; i < 2; ++i)
#pragma unroll
            for (int kk = 0; kk < 2; ++kk) {
                int row = wm * 128 + (qq * 2 + i) * 16 + (lane & 15);
                int cb = ((lane >> 4) * 16 + kk * 64) ^ ((lane & 7) << 4);
                af[i][kk] = *(const short8*)(Al + buf * 32768 + row * 128 + cb);
            }
    };
    auto ldB = [&](int buf) {
#pragma unroll
        for (int n = 0; n < 4; ++n)
#pragma unroll
            for (int kk = 0; kk < 2; ++kk) {
                int row = wn * 64 + n * 16 + (lane & 15);
                int cb = ((lane >> 4) * 16 + kk * 64) ^ ((lane & 7) << 4);
                bfr[n][kk] = *(const short8*)(Bl + buf * 32768 + row * 128 + cb);
            }
    };

#define MFMA_Q(q)                                                                             \
    __builtin_amdgcn_s_setprio(1);                                                            \
    _Pragma("unroll") for (int i = 0; i < 2; ++i)                                             \
        _Pragma("unroll") for (int n = 0; n < 4; ++n)                                         \
            _Pragma("unroll") for (int kk = 0; kk < 2; ++kk)                                  \
                acc[(q)*2 + i][n] = __builtin_amdgcn_mfma_f32_16x16x32_bf16(                  \
                    af[i][kk], bfr[n][kk], acc[(q)*2 + i][n], 0, 0, 0);                       \
    __builtin_amdgcn_s_setprio(0);

#define PH(ldbuf, q, DO_LDB, STAGE_STMT, WAITV)                                               \
    ldA(ldbuf, q);                                                                            \
    if (DO_LDB) ldB(ldbuf);                                                                   \
    STAGE_STMT;                                                                               \
    if (DO_LDB) asm volatile("s_waitcnt lgkmcnt(8)");                                         \
    if (WAITV) asm volatile("s_waitcnt vmcnt(4)");                                            \
    __builtin_amdgcn_s_barrier();                                                             \
    asm volatile("s_waitcnt lgkmcnt(0)");                                                     \
    MFMA_Q(q);                                                                                \
    __builtin_amdgcn_s_barrier();

    auto kloop = [&](int mcur) {
        for (int it = 0; it < NT / 2; ++it) {
            int t1 = (it * 2 + 1) & (NT - 1);
            int t2 = (it * 2 + 2) & (NT - 1);
            int t3 = (it * 2 + 3) & (NT - 1);
            PH(0, 0, true,  stA(1, 0, t1, mcur), false)
            PH(0, 1, false, stA(1, 1, t1, mcur), false)
            PH(0, 2, false, stB(0, 0, t2),       false)
            PH(0, 3, false, stB(0, 1, t2),       true)
            PH(1, 0, true,  stA(0, 0, t2, mcur), false)
            PH(1, 1, false, stA(0, 1, t2, mcur), false)
            PH(1, 2, false, stB(1, 0, t3),       false)
            PH(1, 3, false, stB(1, 1, t3),       true)
        }
    };

    // ---- full-line NT epilogue via LDS transpose (dead buf1.A region, 32 KB) ----
    int rowq4 = (lane >> 4) * 4;
    auto epi = [&](int mbase) {
        char* T = Al + 32768;
#pragma unroll
        for (int p = 0; p < 8; ++p) {
            __builtin_amdgcn_s_barrier();   // prior pass readback done before overwrite
            if (wm == (p >> 2)) {
#pragma unroll
                for (int mi = 0; mi < 2; ++mi) {
                    int mf = (p & 3) * 2 + mi;
                    int rl = mi * 16 + rowq4;
#pragma unroll
                    for (int nf = 0; nf < 4; ++nf) {
                        int c = wn * 64 + nf * 16 + colq;
#pragma unroll
                        for (int q = 0; q < 4; ++q)
                            *(float*)(T + (rl + q) * 1024 + c * 4) = acc[mf][nf][q] + bias[nf];
                    }
                }
            }
            __builtin_amdgcn_s_barrier();
#pragma unroll
            for (int rr = 0; rr < 4; ++rr) {
                int rl = w * 4 + rr;
                f32x4 v = *(const f32x4*)(T + rl * 1024 + lane * 16);
                int grow = mbase + p * 32 + rl;
                __builtin_nontemporal_store(v, (f32x4*)(out + (size_t)grow * VOCAB + n0 + lane * 4));
            }
        }
    };

    // ---- prologue (m-tile 0) ----
    stA(0, 0, 0, ms); stA(0, 1, 0, ms); stB(0, 0, 0); stB(0, 1, 0);
    stB(1, 0, 1); stB(1, 1, 1);
    asm volatile("s_waitcnt vmcnt(4)");
    __builtin_amdgcn_s_barrier();

    kloop(ms);

    // ---- 3 boundaries (r5 semantics): wrap prefetch left buf0.B=B(t0), buf1.B=B(t1).
    // Prestage ONLY buf0.A with A(next,t0) before the epilogue (T aliases buf1.A).
    // FIFO at vmcnt(32): 4 wrapB + 4 prestageA + 32 stores = 40 outstanding
    // -> retires exactly the 8 loads, stores untouched.
#pragma unroll 1
    for (int mt = 1; mt < 4; ++mt) {
        int mn = ms + mt * 256;
        stA(0, 0, 0, mn); stA(0, 1, 0, mn);
        epi(mn - 256);
        asm volatile("s_waitcnt vmcnt(32)" ::: "memory");
        __builtin_amdgcn_s_barrier();
#pragma unroll
        for (int mf = 0; mf < 8; ++mf)
#pragma unroll
            for (int nf = 0; nf < 4; ++nf)
                acc[mf][nf] = f32x4{0.f, 0.f, 0.f, 0.f};
        kloop(mn);
    }
    epi(ms + 768);
#undef PH
#undef MFMA_Q
}

// ---------------- fallback 128^2 2-phase GEMM (if 128 KiB dyn LDS unavailable) ----------------
__global__ __launch_bounds__(256) void gemm_k(const unsigned short* __restrict__ h,
                                              const unsigned short* __restrict__ W2t,
                                              const float* __restrict__ b2,
                                              float* __restrict__ out) {
    __shared__ unsigned short Alds[128 * 64];
    __shared__ unsigned short Blds[128 * 64];
    int m0 = blockIdx.x * 128;
    int n0 = blockIdx.y * 128;
    int tid = threadIdx.x;
    int wave = tid >> 6, lane = tid & 63;
    int wr = (wave >> 1) * 64;
    int wc = (wave & 1) * 64;
    int lrow = lane & 15;
    int khalf = (lane >> 4) * 8;
    f32x4 acc[4][4] = {};
    for (int kt = 0; kt < EMBED; kt += 64) {
#pragma unroll
        for (int i = 0; i < 4; ++i) {
            int base = (wave * 4 + i) * 1024;
            int lin = base + lane * 16;
            int row = lin >> 7;
            int colu = (lin & 127) >> 1;
            GLOAD_LDS16(h + (size_t)(m0 + row) * EMBED + kt + colu, (char*)Alds + base);
            GLOAD_LDS16(W2t + (size_t)(n0 + row) * EMBED + kt + colu, (char*)Blds + base);
        }
        __syncthreads();
#pragma unroll
        for (int kc = 0; kc < 2; ++kc) {
            short8 af[4], bf[4];
#pragma unroll
            for (int m = 0; m < 4; ++m)
                af[m] = *(const short8*)(Alds + (wr + m * 16 + lrow) * 64 + kc * 32 + khalf);
#pragma unroll
            for (int n = 0; n < 4; ++n)
                bf[n] = *(const short8*)(Blds + (wc + n * 16 + lrow) * 64 + kc * 32 + khalf);
#pragma unroll
            for (int m = 0; m < 4; ++m)
#pragma unroll
                for (int n = 0; n < 4; ++n)
                    acc[m][n] = __builtin_amdgcn_mfma_f32_16x16x32_bf16(af[m], bf[n], acc[m][n], 0, 0, 0);
        }
        __syncthreads();
    }
    int colq = lane & 15;
    int rowq = (lane >> 4) * 4;
#pragma unroll
    for (int m = 0; m < 4; ++m)
#pragma unroll
        for (int n = 0; n < 4; ++n) {
            int col = n0 + wc + n * 16 + colq;
            float bias = b2[col];
#pragma unroll
            for (int q = 0; q < 4; ++q)
                out[(size_t)(m0 + wr + m * 16 + rowq + q) * VOCAB + col] = acc[m][n][q] + bias;
        }
}

// ---------------- fallback (ws too small): correct fp32 path ----------------
__global__ __launch_bounds__(256) void naive_k(const int* __restrict__ toks,
                                               const float* __restrict__ W1,
                                               const float* __restrict__ b1,
                                               const float* __restrict__ W2,
                                               const float* __restrict__ b2,
                                               float* __restrict__ out) {
    __shared__ float hs[8][1024];
    int r0 = blockIdx.x * 8;
    int e = threadIdx.x * 4;
    for (int rr = 0; rr < 8; ++rr) {
        int r = r0 + rr, s = r >> 3, b = r & 7;
        int t0 = (s >= 3) ? toks[(s - 3) * BATCH + b] : 0;
        int t1 = (s >= 2) ? toks[(s - 2) * BATCH + b] : 0;
        int t2 = (s >= 1) ? toks[(s - 1) * BATCH + b] : 0;
        float4 vb = *(const float4*)(b1 + e);
        float4 v0 = *(const float4*)(W1 + ((size_t)t0) * EMBED + e);
        float4 v1 = *(const float4*)(W1 + ((size_t)VOCAB + t1) * EMBED + e);
        float4 v2 = *(const float4*)(W1 + ((size_t)2 * VOCAB + t2) * EMBED + e);
        hs[rr][e + 0] = fmaxf(vb.x + v0.x + v1.x + v2.x, 0.0f);
        hs[rr][e + 1] = fmaxf(vb.y + v0.y + v1.y + v2.y, 0.0f);
        hs[rr][e + 2] = fmaxf(vb.z + v0.z + v1.z + v2.z, 0.0f);
        hs[rr][e + 3] = fmaxf(vb.w + v0.w + v1.w + v2.w, 0.0f);
    }
    __syncthreads();
    for (int v = threadIdx.x; v < VOCAB; v += 256) {
        float acc[8];
#pragma unroll
        for (int i = 0; i < 8; ++i) acc[i] = b2[v];
        for (int ee = 0; ee < EMBED; ++ee) {
            float wv = W2[(size_t)ee * VOCAB + v];
#pragma unroll
            for (int i = 0; i < 8; ++i) acc[i] += hs[i][ee] * wv;
        }
#pragma unroll
        for (int i = 0; i < 8; ++i) out[(size_t)(r0 + i) * VOCAB + v] = acc[i];
    }
}

extern "C" void kernel_launch(void* const* d_in, const int* in_sizes, int n_in,
                              void* d_out, int out_size, void* d_ws, size_t ws_size,
                              hipStream_t stream) {
    const int* toks = (const int*)d_in[0];
    const float* W1 = (const float*)d_in[1];
    const float* b1 = (const float*)d_in[2];
    const float* W2 = (const float*)d_in[3];
    const float* b2 = (const float*)d_in[4];
    float* out = (float*)d_out;

    const size_t h_bytes = (size_t)ROWS * EMBED * 2;
    const size_t w2t_bytes = (size_t)VOCAB * EMBED * 2;
    if (ws_size >= h_bytes + w2t_bytes) {
        unsigned short* h = (unsigned short*)d_ws;
        unsigned short* W2t = (unsigned short*)((char*)d_ws + h_bytes);
        prep_k<<<8000 + ROWS, 256, 0, stream>>>(toks, W1, b1, W2, h, W2t);
        hipError_t e = hipFuncSetAttribute(reinterpret_cast<const void*>(gemm8_k),
                                           hipFuncAttributeMaxDynamicSharedMemorySize, 131072);
        if (e == hipSuccess) {
            gemm8_k<<<(ROWS / 1024) * (VOCAB / BN), 512, 131072, stream>>>(h, W2t, b2, out);
        } else {
            gemm_k<<<dim3(ROWS / 128, VOCAB / 128), 256, 0, stream>>>(h, W2t, b2, out);
        }
    } else {
        naive_k<<<ROWS / 8, 256, 0, stream>>>(toks, W1, b1, W2, b2, out);
    }
}